// Round 7
// baseline (290.784 us; speedup 1.0000x reference)
//
#include <hip/hip_runtime.h>

// SLAM layer: out[1,T,M,E,1] = (main[T,M,K] @ relu(x_aux[K,T,Da] @ W[Da,E] + b)[K,T,E] per t)
// T=128, M=512, K=256, Da=256, E=512.
// R7 (= R6 resubmit; R6 hit a GPU-broker timeout, never ran): single fused kernel per
// (t, 64-e slice). Stage 1: aux slice computed into LDS (x_aux staged per-32d, Wc frags
// reg-prefetched). Stage 2: main GEMM with aux read from LDS (zero global latency on A-op)
// and x_main staged f32->bf16 double-buffered. auxc HBM round-trip (67MB) eliminated.

typedef __attribute__((ext_vector_type(8))) short  bf16x8;   // MFMA A/B frag (4 VGPR)
typedef __attribute__((ext_vector_type(4))) float  f32x4;    // MFMA C/D frag
typedef __attribute__((ext_vector_type(4))) unsigned int uint4v;
typedef __attribute__((ext_vector_type(2))) unsigned int uint2v;

#define T_DIM 128
#define M_DIM 512
#define K_DIM 256
#define DA    256
#define DENSE 512
#define WC_G_STRIDE 4096   // Wc: [g=d/8:32][e:512][8] bf16, g stride 512*8=4096 elems

__device__ __forceinline__ unsigned short f2bf(float f) {
    unsigned u = __builtin_bit_cast(unsigned, f);
    unsigned r = (u + 0x7fffu + ((u >> 16) & 1u)) >> 16;   // RNE
    return (unsigned short)r;
}
__device__ __forceinline__ unsigned pack2(float lo, float hi) {
    return (unsigned)f2bf(lo) | ((unsigned)f2bf(hi) << 16);
}

// ---------------- Kernel 0: W [Da][E] f32 -> Wc bf16 chunks [g][e][8] ----------------------
__global__ __launch_bounds__(256) void wchunk_kernel(const float* __restrict__ W,
                                                     unsigned short* __restrict__ Wc) {
    int c = blockIdx.x * 256 + threadIdx.x;   // chunk id = g*DENSE + e
    int g = c >> 9;
    int e = c & 511;
    float f[8];
#pragma unroll
    for (int j = 0; j < 8; ++j) f[j] = W[(g * 8 + j) * DENSE + e];
    uint4v w;
    w.x = pack2(f[0], f[1]); w.y = pack2(f[2], f[3]);
    w.z = pack2(f[4], f[5]); w.w = pack2(f[6], f[7]);
    *reinterpret_cast<uint4v*>(Wc + (size_t)c * 8) = w;
}

// ---------------- Fused kernel: one block = (t, 64-e slice) --------------------------------
// 1024 threads = 16 waves. LDS 96KB: [0,64K) staging scratch (stage1: xa dbuf 2x16K;
// stage2: main dbuf 2x32K), [64K,96K) aux chunk buffer [g=k/8:32][e:64][8] bf16.
__global__ __launch_bounds__(1024, 4) void fused_kernel(const float* __restrict__ xmain,
                                                        const float* __restrict__ xaux,
                                                        const unsigned short* __restrict__ Wc,
                                                        const float* __restrict__ bias,
                                                        float* __restrict__ out) {
    __shared__ char lds[98304];
    char* const auxl = lds + 65536;

    const int bid = blockIdx.x;                    // 1024 blocks
    const int swz = (bid & 7) * 128 + (bid >> 3);  // XCD-grouped, bijective (1024%8==0)
    const int t   = swz >> 3;                      // 16 consecutive t per XCD
    const int eb  = (swz & 7) * 64;

    const int tid  = threadIdx.x;
    const int lane = tid & 63, wid = tid >> 6;
    const int l15  = lane & 15, lg = lane >> 4;
    const int srow = tid >> 3;                     // staging row 0..127 (+128 per pass)
    const int sq   = tid & 7;                      // staging quad-of-4-floats

    // ================= Stage 1: aux[k=256][e=eb..eb+64) = relu(xa[t] @ W + b) ==============
    const int wk = (wid >> 2) * 64;                // wave k group (4 x 64k)
    const int we = (wid & 3) * 16;                 // wave e group (4 x 16e)
    const float bias_v = bias[eb + we + l15];

    f32x4 acc1[4];
#pragma unroll
    for (int i = 0; i < 4; ++i) acc1[i] = (f32x4)0.0f;

#define XA_LOAD(regs, dsv)                                                                 \
    do {                                                                                   \
        _Pragma("unroll") for (int p = 0; p < 2; ++p)                                      \
            regs[p] = *reinterpret_cast<const f32x4*>(                                     \
                xaux + (size_t)(p * 128 + srow) * (T_DIM * DA) + (size_t)t * DA            \
                     + (dsv) * 32 + sq * 4);                                               \
    } while (0)

#define XA_WRITE(regs, bufv)                                                               \
    do {                                                                                   \
        _Pragma("unroll") for (int p = 0; p < 2; ++p) {                                    \
            uint2v o;                                                                      \
            o.x = pack2(regs[p].x, regs[p].y);                                             \
            o.y = pack2(regs[p].z, regs[p].w);                                             \
            *reinterpret_cast<uint2v*>(lds + (bufv) * 16384 + (sq >> 1) * 4096             \
                                          + (p * 128 + srow) * 16 + (sq & 1) * 8) = o;     \
        }                                                                                  \
    } while (0)

#define WF_LOAD(dst, dsv)                                                                  \
    dst = *reinterpret_cast<const bf16x8*>(                                                \
        Wc + (size_t)((dsv) * 4 + lg) * WC_G_STRIDE + (size_t)(eb + we + l15) * 8)

    {
        f32x4 s1[2];
        bf16x8 wfA, wfB;
        XA_LOAD(s1, 0);
        WF_LOAD(wfA, 0);
        XA_WRITE(s1, 0);
        __syncthreads();
#pragma unroll
        for (int ds = 0; ds < 8; ++ds) {
            const int cur = ds & 1;
            if (ds < 7) { XA_LOAD(s1, ds + 1); WF_LOAD(wfB, ds + 1); }
            bf16x8 xf[4];
#pragma unroll
            for (int i = 0; i < 4; ++i)
                xf[i] = *reinterpret_cast<const bf16x8*>(
                    lds + cur * 16384 + lg * 4096 + (wk + i * 16 + l15) * 16);
#pragma unroll
            for (int i = 0; i < 4; ++i)
                acc1[i] = __builtin_amdgcn_mfma_f32_16x16x32_bf16(xf[i], wfA, acc1[i], 0, 0, 0);
            if (ds < 7) { XA_WRITE(s1, cur ^ 1); __syncthreads(); wfA = wfB; }
        }
    }
#undef XA_LOAD
#undef XA_WRITE
#undef WF_LOAD

    // epilogue: +bias, relu, pack 4 consecutive k -> aux chunk buffer (region B)
#pragma unroll
    for (int i = 0; i < 4; ++i) {
        int k0 = wk + i * 16 + lg * 4;             // k0&7 in {0,4}
        float v0 = fmaxf(acc1[i].x + bias_v, 0.0f);
        float v1 = fmaxf(acc1[i].y + bias_v, 0.0f);
        float v2 = fmaxf(acc1[i].z + bias_v, 0.0f);
        float v3 = fmaxf(acc1[i].w + bias_v, 0.0f);
        uint2v o; o.x = pack2(v0, v1); o.y = pack2(v2, v3);
        *reinterpret_cast<uint2v*>(auxl + (k0 >> 3) * 1024 + (we + l15) * 16 + (k0 & 7) * 2) = o;
    }

    // ================= Stage 2: out[t][m][eb+e] = sum_k aux[k][e] * main[m][k] =============
    const int wm  = (wid >> 1) * 64;               // wave m group (8 x 64m)
    const int we2 = (wid & 1) * 32;                // wave e group (2 x 32e)

    f32x4 acc2[2][4];
#pragma unroll
    for (int i = 0; i < 2; ++i)
#pragma unroll
        for (int j = 0; j < 4; ++j) acc2[i][j] = (f32x4)0.0f;

#define MS_LOAD(regs, ksv)                                                                 \
    do {                                                                                   \
        _Pragma("unroll") for (int p = 0; p < 4; ++p)                                      \
            regs[p] = *reinterpret_cast<const f32x4*>(                                     \
                xmain + (size_t)t * (M_DIM * K_DIM) + (size_t)(p * 128 + srow) * K_DIM     \
                      + (ksv) * 32 + sq * 4);                                              \
    } while (0)

#define MS_WRITE(regs, bufv)                                                               \
    do {                                                                                   \
        _Pragma("unroll") for (int p = 0; p < 4; ++p) {                                    \
            uint2v o;                                                                      \
            o.x = pack2(regs[p].x, regs[p].y);                                             \
            o.y = pack2(regs[p].z, regs[p].w);                                             \
            *reinterpret_cast<uint2v*>(lds + (bufv) * 32768 + (sq >> 1) * 8192             \
                                          + (p * 128 + srow) * 16 + (sq & 1) * 8) = o;     \
        }                                                                                  \
    } while (0)

    {
        f32x4 s2[4];
        MS_LOAD(s2, 0);                            // global loads: issue before barrier
        __syncthreads();                           // stage1 region-A reads + aux writes done
        MS_WRITE(s2, 0);
        __syncthreads();                           // ms buf0 + aux visible
#pragma unroll
        for (int ks = 0; ks < 8; ++ks) {
            const int cur = ks & 1;
            if (ks < 7) MS_LOAD(s2, ks + 1);       // issue-early next-slice loads
            bf16x8 af[2], mf[4];
#pragma unroll
            for (int i = 0; i < 2; ++i)
                af[i] = *reinterpret_cast<const bf16x8*>(
                    auxl + (ks * 4 + lg) * 1024 + (we2 + i * 16 + l15) * 16);
#pragma unroll
            for (int j = 0; j < 4; ++j)
                mf[j] = *reinterpret_cast<const bf16x8*>(
                    lds + cur * 32768 + lg * 8192 + (wm + j * 16 + l15) * 16);
#pragma unroll
            for (int i = 0; i < 2; ++i)
#pragma unroll
                for (int j = 0; j < 4; ++j)
                    acc2[i][j] = __builtin_amdgcn_mfma_f32_16x16x32_bf16(af[i], mf[j], acc2[i][j], 0, 0, 0);
            if (ks < 7) { MS_WRITE(s2, cur ^ 1); __syncthreads(); }
        }
    }
#undef MS_LOAD
#undef MS_WRITE

    // store: 4 consecutive e per reg quad; lanes lg=0..3 of same m fill a full 64B line
#pragma unroll
    for (int i = 0; i < 2; ++i) {
        int e0 = eb + we2 + i * 16 + lg * 4;
#pragma unroll
        for (int j = 0; j < 4; ++j) {
            int m = wm + j * 16 + l15;
            *reinterpret_cast<f32x4*>(out + (size_t)t * (M_DIM * DENSE) + (size_t)m * DENSE + e0) = acc2[i][j];
        }
    }
}

extern "C" void kernel_launch(void* const* d_in, const int* in_sizes, int n_in,
                              void* d_out, int out_size, void* d_ws, size_t ws_size,
                              hipStream_t stream) {
    const float* x_main = (const float*)d_in[0];   // [1,128,512,256]
    const float* x_aux  = (const float*)d_in[1];   // [256,128,256]
    const float* W      = (const float*)d_in[2];   // [256,512]
    const float* b      = (const float*)d_in[3];   // [512]
    float* out = (float*)d_out;                    // [1,128,512,512,1]

    unsigned short* Wc = (unsigned short*)d_ws;    // 256 KiB only

    wchunk_kernel<<<64, 256, 0, stream>>>(W, Wc);
    fused_kernel<<<1024, 1024, 0, stream>>>(x_main, x_aux, Wc, b, out);
}